// Round 6
// baseline (160.636 us; speedup 1.0000x reference)
//
#include <hip/hip_runtime.h>
#include <hip/hip_fp16.h>

// score[e] = relu(h[src[e]]@W1s + h[dst[e]]@W1d + b1) @ W2 + b2
// N_NODES=100000, N_EDGES=1600000, H=64.
// Phase 1: per-node P = h@W1s + b1, Q = h@W1d (fp16, 25.6 MB, L2/L3-resident).
//   h tile: global -> LDS (coalesced) -> 64 VGPRs/lane (one node per lane).
//   Steady-state inner loop touches ONLY the scalar pipe (wave-uniform W rows,
//   sK$-resident) + VALU FMA. No ds_read in the loop -> no lgkmcnt(0) drains
//   from SMEM/DS mixing.
// Phase 2: per-edge gather P[src],Q[dst] + relu + dot(w2). At the random-line
//   gather floor (~3.6 TB/s beyond-L2) — unchanged.

#define HF  64
#define TN  64    // nodes per block tile (1 per lane)
#define PAD 68    // floats per LDS row: 272 B, 16B-aligned for b128 reads

// ---------------- Phase 1: per-node projection ----------------
__global__ __launch_bounds__(512) void node_proj_kernel(
    const float* __restrict__ h, const float* __restrict__ W1,
    const float* __restrict__ b1, __half* __restrict__ P,
    __half* __restrict__ Q, int n_nodes)
{
    __shared__ float hs[TN * PAD];   // 64 * 68 * 4 = 17.4 KB

    const int tid  = threadIdx.x;
    const int lane = tid & 63;
    const int wave = __builtin_amdgcn_readfirstlane(tid >> 6);  // 0..7
    const int c0   = wave * 16;          // column strip in [0,128)
    const bool isQ = c0 >= 64;
    const int ccol = c0 & 63;

    const float* wbase = W1 + (isQ ? (HF * HF) : 0) + ccol;  // wave-uniform
    __half* const outh = (isQ ? Q : P) + ccol;

    const int n0   = blockIdx.x * TN;
    const int nrow = (n_nodes - n0 < TN) ? (n_nodes - n0) : TN;   // >= 1

    // ---- stage h[n0 : n0+nrow][0:64] into LDS, coalesced ----
    {
        const int maxf4 = nrow * 16;                       // float4 count
        const float4* hv = (const float4*)(h + (size_t)n0 * HF);
        #pragma unroll
        for (int it = 0; it < 2; ++it) {
            const int idx  = tid + it * 512;               // 0..1023
            const int cidx = (idx < maxf4) ? idx : 0;      // clamp (tail)
            const float4 v = hv[cidx];
            const int row = idx >> 4;
            const int c4  = (idx & 15) * 4;
            *(float4*)&hs[row * PAD + c4] = v;
        }
    }
    __syncthreads();

    // ---- pull my node's row into VGPRs (one-time LDS reads) ----
    float hreg[64];
    {
        const float* r = &hs[lane * PAD];
        #pragma unroll
        for (int k4 = 0; k4 < 16; ++k4) {
            const float4 v = *(const float4*)(r + k4 * 4);
            hreg[k4 * 4 + 0] = v.x;
            hreg[k4 * 4 + 1] = v.y;
            hreg[k4 * 4 + 2] = v.z;
            hreg[k4 * 4 + 3] = v.w;
        }
    }

    // ---- steady state: scalar-pipe W + VALU FMA only ----
    float acc[16];
    #pragma unroll
    for (int j = 0; j < 16; ++j) acc[j] = isQ ? 0.0f : b1[ccol + j];

    #pragma unroll
    for (int k = 0; k < 64; ++k) {
        const float a = hreg[k];
        const float* w = wbase + k * HF;   // uniform -> s_load_dwordx16
        #pragma unroll
        for (int j = 0; j < 16; ++j)
            acc[j] = fmaf(a, w[j], acc[j]);
    }

    if (lane < nrow) {
        union { uint4 u[2]; __half2 hh[8]; } pk;
        #pragma unroll
        for (int j = 0; j < 8; ++j)
            pk.hh[j] = __floats2half2_rn(acc[2 * j], acc[2 * j + 1]);
        __half* base = outh + (size_t)(n0 + lane) * HF;
        *(uint4*)(base)     = pk.u[0];
        *(uint4*)(base + 8) = pk.u[1];
    }
}

// ---------------- Phase 2: per-edge score (at gather floor) ----------------
__device__ __forceinline__ float dot8_relu(uint4 pv, uint4 qv, float4 wa, float4 wb) {
    const __half2* ph = (const __half2*)&pv;
    const __half2* qh = (const __half2*)&qv;
    const float2 p0 = __half22float2(ph[0]), q0 = __half22float2(qh[0]);
    const float2 p1 = __half22float2(ph[1]), q1 = __half22float2(qh[1]);
    const float2 p2 = __half22float2(ph[2]), q2 = __half22float2(qh[2]);
    const float2 p3 = __half22float2(ph[3]), q3 = __half22float2(qh[3]);
    float acc = 0.f;
    acc = fmaf(fmaxf(p0.x + q0.x, 0.f), wa.x, acc);
    acc = fmaf(fmaxf(p0.y + q0.y, 0.f), wa.y, acc);
    acc = fmaf(fmaxf(p1.x + q1.x, 0.f), wa.z, acc);
    acc = fmaf(fmaxf(p1.y + q1.y, 0.f), wa.w, acc);
    acc = fmaf(fmaxf(p2.x + q2.x, 0.f), wb.x, acc);
    acc = fmaf(fmaxf(p2.y + q2.y, 0.f), wb.y, acc);
    acc = fmaf(fmaxf(p3.x + q3.x, 0.f), wb.z, acc);
    acc = fmaf(fmaxf(p3.y + q3.y, 0.f), wb.w, acc);
    return acc;
}

__device__ __forceinline__ float red8(float v) {
    v += __shfl_xor(v, 4, 8);
    v += __shfl_xor(v, 2, 8);
    v += __shfl_xor(v, 1, 8);
    return v;
}

__global__ __launch_bounds__(256) void edge_score_kernel(
    const __half* __restrict__ P, const __half* __restrict__ Q,
    const int* __restrict__ src, const int* __restrict__ dst,
    const float* __restrict__ W2, const float* __restrict__ b2,
    float* __restrict__ out, int n_edges)
{
    const int tid   = blockIdx.x * 256 + threadIdx.x;
    const int sub   = threadIdx.x & 7;
    const int group = tid >> 3;
    const int j0    = sub * 8;
    const int e0    = group * 8;
    if (e0 >= n_edges) return;

    const float4 w2a = *(const float4*)(W2 + j0);
    const float4 w2b = *(const float4*)(W2 + j0 + 4);
    const float bias2 = b2[0];

    if (e0 + 8 <= n_edges) {
        const int4 sA = *(const int4*)(src + e0);
        const int4 sB = *(const int4*)(src + e0 + 4);
        const int4 dA = *(const int4*)(dst + e0);
        const int4 dB = *(const int4*)(dst + e0 + 4);

        const uint4 p0 = *(const uint4*)(P + (size_t)sA.x * HF + j0);
        const uint4 p1 = *(const uint4*)(P + (size_t)sA.y * HF + j0);
        const uint4 p2 = *(const uint4*)(P + (size_t)sA.z * HF + j0);
        const uint4 p3 = *(const uint4*)(P + (size_t)sA.w * HF + j0);
        const uint4 p4 = *(const uint4*)(P + (size_t)sB.x * HF + j0);
        const uint4 p5 = *(const uint4*)(P + (size_t)sB.y * HF + j0);
        const uint4 p6 = *(const uint4*)(P + (size_t)sB.z * HF + j0);
        const uint4 p7 = *(const uint4*)(P + (size_t)sB.w * HF + j0);
        const uint4 q0 = *(const uint4*)(Q + (size_t)dA.x * HF + j0);
        const uint4 q1 = *(const uint4*)(Q + (size_t)dA.y * HF + j0);
        const uint4 q2 = *(const uint4*)(Q + (size_t)dA.z * HF + j0);
        const uint4 q3 = *(const uint4*)(Q + (size_t)dA.w * HF + j0);
        const uint4 q4 = *(const uint4*)(Q + (size_t)dB.x * HF + j0);
        const uint4 q5 = *(const uint4*)(Q + (size_t)dB.y * HF + j0);
        const uint4 q6 = *(const uint4*)(Q + (size_t)dB.z * HF + j0);
        const uint4 q7 = *(const uint4*)(Q + (size_t)dB.w * HF + j0);

        float s0 = red8(dot8_relu(p0, q0, w2a, w2b));
        float s1 = red8(dot8_relu(p1, q1, w2a, w2b));
        float s2 = red8(dot8_relu(p2, q2, w2a, w2b));
        float s3 = red8(dot8_relu(p3, q3, w2a, w2b));
        float s4 = red8(dot8_relu(p4, q4, w2a, w2b));
        float s5 = red8(dot8_relu(p5, q5, w2a, w2b));
        float s6 = red8(dot8_relu(p6, q6, w2a, w2b));
        float s7 = red8(dot8_relu(p7, q7, w2a, w2b));

        if (sub == 0) {
            *(float4*)(out + e0)     = make_float4(s0 + bias2, s1 + bias2,
                                                   s2 + bias2, s3 + bias2);
            *(float4*)(out + e0 + 4) = make_float4(s4 + bias2, s5 + bias2,
                                                   s6 + bias2, s7 + bias2);
        }
    } else {
        for (int e = e0; e < n_edges; ++e) {
            const int s = src[e];
            const int d = dst[e];
            const uint4 pv = *(const uint4*)(P + (size_t)s * HF + j0);
            const uint4 qv = *(const uint4*)(Q + (size_t)d * HF + j0);
            float sc = red8(dot8_relu(pv, qv, w2a, w2b));
            if (sub == 0) out[e] = sc + bias2;
        }
    }
}

extern "C" void kernel_launch(void* const* d_in, const int* in_sizes, int n_in,
                              void* d_out, int out_size, void* d_ws, size_t ws_size,
                              hipStream_t stream) {
    const float* h   = (const float*)d_in[0];
    const int*   src = (const int*)d_in[1];
    const int*   dst = (const int*)d_in[2];
    const float* W1  = (const float*)d_in[3];
    const float* b1  = (const float*)d_in[4];
    const float* W2  = (const float*)d_in[5];
    const float* b2  = (const float*)d_in[6];
    float* out = (float*)d_out;

    const int n_nodes = in_sizes[0] / HF;
    const int n_edges = in_sizes[1];

    __half* P = (__half*)d_ws;
    __half* Q = P + (size_t)n_nodes * HF;

    const int nblocks1 = (n_nodes + TN - 1) / TN;        // 64 nodes/block, 8 waves
    node_proj_kernel<<<nblocks1, 512, 0, stream>>>(h, W1, b1, P, Q, n_nodes);

    const int ngroups  = (n_edges + 7) / 8;              // 8 edges per 8-lane group
    const int nblocks2 = (ngroups + 31) / 32;            // 32 groups per 256-thr block
    edge_score_kernel<<<nblocks2, 256, 0, stream>>>(P, Q, src, dst, W2, b2, out, n_edges);
}

// Round 7
// 149.699 us; speedup vs baseline: 1.0731x; 1.0731x over previous
//
#include <hip/hip_runtime.h>
#include <hip/hip_fp16.h>

// score[e] = relu(h[src[e]]@W1s + h[dst[e]]@W1d + b1) @ W2 + b2
// N_NODES=100000, N_EDGES=1600000, H=64.
// Phase 1 (node_proj): GEMM [N x 64] @ [64 x 128] via bf16 MFMA 16x16x32.
//   Per 256-thr block: 64 nodes. h staged fp32->LDS (coalesced), A-frags from
//   LDS (2-way-free b128), B-frags from L1-resident W1, 16 MFMA/wave, epilogue
//   transposed through LDS for coalesced fp16 stores. Streaming-bound (~8 us).
// Phase 2 (edge_score): per-edge gather P[src],Q[dst] + relu + dot(w2).
//   Pinned at the random-128B-line gather floor (~3.6 TB/s beyond-L2).

#define HF  64
#define PADF 68    // fp32 LDS row pitch (stage):  64*68*4  = 17408 B
#define PADH 136   // fp16 LDS row pitch (epilog): 64*136*2 = 17408 B

typedef __attribute__((ext_vector_type(8))) short bf16x8;
typedef __attribute__((ext_vector_type(4))) float f32x4;

__device__ __forceinline__ short f2bf(float x) {
    unsigned u = __builtin_bit_cast(unsigned, x);
    unsigned r = (u + 0x7fffu + ((u >> 16) & 1u)) >> 16;
    return (short)r;
}

// ---------------- Phase 1: node projection via MFMA ----------------
__global__ __launch_bounds__(256) void node_proj_kernel(
    const float* __restrict__ h, const float* __restrict__ W1,
    const float* __restrict__ b1, __half* __restrict__ P,
    __half* __restrict__ Q, int n_nodes)
{
    __shared__ float hs[64 * PADF];          // reused as fp16 [64][PADH] later

    const int tid  = threadIdx.x;
    const int wave = tid >> 6;               // 0..3: 16-node strip
    const int lane = tid & 63;
    const int q    = lane >> 4;              // quad 0..3
    const int n    = lane & 15;

    const int n0   = blockIdx.x * 64;
    const int nrow = (n_nodes - n0 < 64) ? (n_nodes - n0) : 64;

    // ---- stage h[n0:n0+64][0:64] fp32 -> LDS, coalesced ----
    {
        const int maxf4 = nrow * 16;
        const float4* hv = (const float4*)(h + (size_t)n0 * HF);
        #pragma unroll
        for (int it = 0; it < 4; ++it) {
            const int idx  = tid + it * 256;          // 0..1023
            const int cidx = (idx < maxf4) ? idx : 0;
            const float4 v = hv[cidx];
            const int row = idx >> 4;
            const int c4  = (idx & 15) * 4;
            *(float4*)&hs[row * PADF + c4] = v;
        }
    }

    // ---- B fragments: B[k][col], k = kb*32 + q*8 + j, col = t*16 + n ----
    // t<4 -> P cols (W1 rows 0..63); t>=4 -> Q cols (W1 rows 64..127).
    bf16x8 bfrag[8][2];
    #pragma unroll
    for (int t = 0; t < 8; ++t) {
        const float* wb = W1 + ((t >= 4) ? HF * HF : 0) + (t & 3) * 16 + n;
        #pragma unroll
        for (int kb = 0; kb < 2; ++kb) {
            #pragma unroll
            for (int j = 0; j < 8; ++j)
                bfrag[t][kb][j] = f2bf(wb[(kb * 32 + q * 8 + j) * HF]);
        }
    }

    __syncthreads();

    // ---- A fragments: A[m][k], m = wave*16 + n, k = kb*32 + q*8 + j ----
    bf16x8 afrag[2];
    {
        const float* r = &hs[(wave * 16 + n) * PADF];
        #pragma unroll
        for (int kb = 0; kb < 2; ++kb) {
            const float* rk = r + kb * 32 + q * 8;
            #pragma unroll
            for (int j = 0; j < 8; ++j) afrag[kb][j] = f2bf(rk[j]);
        }
    }

    // ---- MFMA: 8 N-tiles x 2 K-halves ----
    f32x4 acc[8];
    #pragma unroll
    for (int t = 0; t < 8; ++t) {
        acc[t] = (f32x4){0.f, 0.f, 0.f, 0.f};
        acc[t] = __builtin_amdgcn_mfma_f32_16x16x32_bf16(afrag[0], bfrag[t][0], acc[t], 0, 0, 0);
        acc[t] = __builtin_amdgcn_mfma_f32_16x16x32_bf16(afrag[1], bfrag[t][1], acc[t], 0, 0, 0);
    }

    __syncthreads();   // done reading fp32 tile; reuse LDS as fp16

    // ---- epilogue: C[row][col] -> LDS fp16 (add b1 on P cols) ----
    // C/D layout: col = lane&15 (=n), row = q*4 + reg, rows offset by wave*16.
    __half* hs2 = (__half*)hs;               // [64][PADH]
    #pragma unroll
    for (int t = 0; t < 8; ++t) {
        const float bb = (t < 4) ? b1[(t & 3) * 16 + n] : 0.0f;
        #pragma unroll
        for (int r = 0; r < 4; ++r) {
            const int row = wave * 16 + q * 4 + r;
            hs2[row * PADH + t * 16 + n] = __float2half(acc[t][r] + bb);
        }
    }
    __syncthreads();

    // ---- coalesced fp16 stores: row cols 0..63 -> P, 64..127 -> Q ----
    #pragma unroll
    for (int it = 0; it < 4; ++it) {
        const int idx  = tid + it * 256;      // 0..1023 uint4s
        const int row  = idx >> 4;
        const int part = idx & 15;
        if (row < nrow) {
            const uint4 v = *(const uint4*)&hs2[row * PADH + part * 8];
            __half* dstp = (part < 8)
                ? (P + (size_t)(n0 + row) * HF + part * 8)
                : (Q + (size_t)(n0 + row) * HF + (part - 8) * 8);
            *(uint4*)dstp = v;
        }
    }
}

// ---------------- Phase 2: per-edge score (at gather floor) ----------------
__device__ __forceinline__ float dot8_relu(uint4 pv, uint4 qv, float4 wa, float4 wb) {
    const __half2* ph = (const __half2*)&pv;
    const __half2* qh = (const __half2*)&qv;
    const float2 p0 = __half22float2(ph[0]), q0 = __half22float2(qh[0]);
    const float2 p1 = __half22float2(ph[1]), q1 = __half22float2(qh[1]);
    const float2 p2 = __half22float2(ph[2]), q2 = __half22float2(qh[2]);
    const float2 p3 = __half22float2(ph[3]), q3 = __half22float2(qh[3]);
    float acc = 0.f;
    acc = fmaf(fmaxf(p0.x + q0.x, 0.f), wa.x, acc);
    acc = fmaf(fmaxf(p0.y + q0.y, 0.f), wa.y, acc);
    acc = fmaf(fmaxf(p1.x + q1.x, 0.f), wa.z, acc);
    acc = fmaf(fmaxf(p1.y + q1.y, 0.f), wa.w, acc);
    acc = fmaf(fmaxf(p2.x + q2.x, 0.f), wb.x, acc);
    acc = fmaf(fmaxf(p2.y + q2.y, 0.f), wb.y, acc);
    acc = fmaf(fmaxf(p3.x + q3.x, 0.f), wb.z, acc);
    acc = fmaf(fmaxf(p3.y + q3.y, 0.f), wb.w, acc);
    return acc;
}

__device__ __forceinline__ float red8(float v) {
    v += __shfl_xor(v, 4, 8);
    v += __shfl_xor(v, 2, 8);
    v += __shfl_xor(v, 1, 8);
    return v;
}

__global__ __launch_bounds__(256) void edge_score_kernel(
    const __half* __restrict__ P, const __half* __restrict__ Q,
    const int* __restrict__ src, const int* __restrict__ dst,
    const float* __restrict__ W2, const float* __restrict__ b2,
    float* __restrict__ out, int n_edges)
{
    const int tid   = blockIdx.x * 256 + threadIdx.x;
    const int sub   = threadIdx.x & 7;
    const int group = tid >> 3;
    const int j0    = sub * 8;
    const int e0    = group * 8;
    if (e0 >= n_edges) return;

    const float4 w2a = *(const float4*)(W2 + j0);
    const float4 w2b = *(const float4*)(W2 + j0 + 4);
    const float bias2 = b2[0];

    if (e0 + 8 <= n_edges) {
        const int4 sA = *(const int4*)(src + e0);
        const int4 sB = *(const int4*)(src + e0 + 4);
        const int4 dA = *(const int4*)(dst + e0);
        const int4 dB = *(const int4*)(dst + e0 + 4);

        const uint4 p0 = *(const uint4*)(P + (size_t)sA.x * HF + j0);
        const uint4 p1 = *(const uint4*)(P + (size_t)sA.y * HF + j0);
        const uint4 p2 = *(const uint4*)(P + (size_t)sA.z * HF + j0);
        const uint4 p3 = *(const uint4*)(P + (size_t)sA.w * HF + j0);
        const uint4 p4 = *(const uint4*)(P + (size_t)sB.x * HF + j0);
        const uint4 p5 = *(const uint4*)(P + (size_t)sB.y * HF + j0);
        const uint4 p6 = *(const uint4*)(P + (size_t)sB.z * HF + j0);
        const uint4 p7 = *(const uint4*)(P + (size_t)sB.w * HF + j0);
        const uint4 q0 = *(const uint4*)(Q + (size_t)dA.x * HF + j0);
        const uint4 q1 = *(const uint4*)(Q + (size_t)dA.y * HF + j0);
        const uint4 q2 = *(const uint4*)(Q + (size_t)dA.z * HF + j0);
        const uint4 q3 = *(const uint4*)(Q + (size_t)dA.w * HF + j0);
        const uint4 q4 = *(const uint4*)(Q + (size_t)dB.x * HF + j0);
        const uint4 q5 = *(const uint4*)(Q + (size_t)dB.y * HF + j0);
        const uint4 q6 = *(const uint4*)(Q + (size_t)dB.z * HF + j0);
        const uint4 q7 = *(const uint4*)(Q + (size_t)dB.w * HF + j0);

        float s0 = red8(dot8_relu(p0, q0, w2a, w2b));
        float s1 = red8(dot8_relu(p1, q1, w2a, w2b));
        float s2 = red8(dot8_relu(p2, q2, w2a, w2b));
        float s3 = red8(dot8_relu(p3, q3, w2a, w2b));
        float s4 = red8(dot8_relu(p4, q4, w2a, w2b));
        float s5 = red8(dot8_relu(p5, q5, w2a, w2b));
        float s6 = red8(dot8_relu(p6, q6, w2a, w2b));
        float s7 = red8(dot8_relu(p7, q7, w2a, w2b));

        if (sub == 0) {
            *(float4*)(out + e0)     = make_float4(s0 + bias2, s1 + bias2,
                                                   s2 + bias2, s3 + bias2);
            *(float4*)(out + e0 + 4) = make_float4(s4 + bias2, s5 + bias2,
                                                   s6 + bias2, s7 + bias2);
        }
    } else {
        for (int e = e0; e < n_edges; ++e) {
            const int s = src[e];
            const int d = dst[e];
            const uint4 pv = *(const uint4*)(P + (size_t)s * HF + j0);
            const uint4 qv = *(const uint4*)(Q + (size_t)d * HF + j0);
            float sc = red8(dot8_relu(pv, qv, w2a, w2b));
            if (sub == 0) out[e] = sc + bias2;
        }
    }
}

extern "C" void kernel_launch(void* const* d_in, const int* in_sizes, int n_in,
                              void* d_out, int out_size, void* d_ws, size_t ws_size,
                              hipStream_t stream) {
    const float* h   = (const float*)d_in[0];
    const int*   src = (const int*)d_in[1];
    const int*   dst = (const int*)d_in[2];
    const float* W1  = (const float*)d_in[3];
    const float* b1  = (const float*)d_in[4];
    const float* W2  = (const float*)d_in[5];
    const float* b2  = (const float*)d_in[6];
    float* out = (float*)d_out;

    const int n_nodes = in_sizes[0] / HF;
    const int n_edges = in_sizes[1];

    __half* P = (__half*)d_ws;
    __half* Q = P + (size_t)n_nodes * HF;

    const int nblocks1 = (n_nodes + 63) / 64;            // 64 nodes per block
    node_proj_kernel<<<nblocks1, 256, 0, stream>>>(h, W1, b1, P, Q, n_nodes);

    const int ngroups  = (n_edges + 7) / 8;              // 8 edges per 8-lane group
    const int nblocks2 = (ngroups + 31) / 32;            // 32 groups per 256-thr block
    edge_score_kernel<<<nblocks2, 256, 0, stream>>>(P, Q, src, dst, W2, b2, out, n_edges);
}

// Round 8
// 145.678 us; speedup vs baseline: 1.1027x; 1.0276x over previous
//
#include <hip/hip_runtime.h>
#include <hip/hip_fp16.h>

// score[e] = relu(h[src[e]]@W1s + h[dst[e]]@W1d + b1) @ W2 + b2
// N_NODES=100000, N_EDGES=1600000, H=64.
// Phase 1 (node_proj): GEMM [N x 64] @ [64 x 128] via bf16 MFMA 16x16x32.
//   A-frags straight from global h (line-efficient: 16 x 128B spans/instr pair),
//   B-frags built once per block (2 tiles amortized), LDS only for the
//   store-transpose epilogue. Pure 51.2 MB stream -> ~10 us target.
// Phase 2 (edge_score): per-edge gather P[src],Q[dst] + relu + dot(w2).
//   Pinned at the random-128B-line gather floor (~3.6 TB/s beyond-L2).

#define HF   64
#define PADH 136   // fp16 LDS row pitch (epilogue): 64*136*2 = 17408 B
#define TPB  2     // 64-node tiles per block

typedef __attribute__((ext_vector_type(8))) short bf16x8;
typedef __attribute__((ext_vector_type(4))) float f32x4;

__device__ __forceinline__ short f2bf(float x) {
    unsigned u = __builtin_bit_cast(unsigned, x);
    unsigned r = (u + 0x7fffu + ((u >> 16) & 1u)) >> 16;
    return (short)r;
}

// ---------------- Phase 1: node projection via MFMA ----------------
__global__ __launch_bounds__(256) void node_proj_kernel(
    const float* __restrict__ h, const float* __restrict__ W1,
    const float* __restrict__ b1, __half* __restrict__ P,
    __half* __restrict__ Q, int n_nodes)
{
    __shared__ __half eb[64 * PADH];         // epilogue transpose buffer

    const int tid  = threadIdx.x;
    const int wave = tid >> 6;               // 0..3: 16-node strip
    const int lane = tid & 63;
    const int q    = lane >> 4;              // quad 0..3
    const int n    = lane & 15;

    // ---- B fragments once per block: B[k][col], k=kb*32+q*8+j, col=t*16+n --
    // t<4 -> P cols (W1 rows 0..63); t>=4 -> Q cols (W1 rows 64..127).
    bf16x8 bfrag[8][2];
    #pragma unroll
    for (int t = 0; t < 8; ++t) {
        const float* wb = W1 + ((t >= 4) ? HF * HF : 0) + (t & 3) * 16 + n;
        #pragma unroll
        for (int kb = 0; kb < 2; ++kb) {
            #pragma unroll
            for (int j = 0; j < 8; ++j)
                bfrag[t][kb][j] = f2bf(wb[(kb * 32 + q * 8 + j) * HF]);
        }
    }
    const float bias_n = b1[0 * 16 + n];     // biases for t=0..3 at this n
    const float bias_n1 = b1[1 * 16 + n];
    const float bias_n2 = b1[2 * 16 + n];
    const float bias_n3 = b1[3 * 16 + n];

    for (int it = 0; it < TPB; ++it) {
        const int tile = blockIdx.x * TPB + it;
        const int n0   = tile * 64;
        if (n0 >= n_nodes) break;            // block-uniform
        const int nrow = (n_nodes - n0 < 64) ? (n_nodes - n0) : 64;

        // ---- A fragments direct from global: A[m][k], m=wave*16+n ----
        bf16x8 a0, a1;
        {
            int row = n0 + wave * 16 + n;
            if (row >= n_nodes) row = n_nodes - 1;
            const float* hr = h + (size_t)row * HF + q * 8;
            const float4 u0 = *(const float4*)(hr);
            const float4 u1 = *(const float4*)(hr + 4);
            const float4 v0 = *(const float4*)(hr + 32);
            const float4 v1 = *(const float4*)(hr + 36);
            a0[0] = f2bf(u0.x); a0[1] = f2bf(u0.y); a0[2] = f2bf(u0.z); a0[3] = f2bf(u0.w);
            a0[4] = f2bf(u1.x); a0[5] = f2bf(u1.y); a0[6] = f2bf(u1.z); a0[7] = f2bf(u1.w);
            a1[0] = f2bf(v0.x); a1[1] = f2bf(v0.y); a1[2] = f2bf(v0.z); a1[3] = f2bf(v0.w);
            a1[4] = f2bf(v1.x); a1[5] = f2bf(v1.y); a1[6] = f2bf(v1.z); a1[7] = f2bf(v1.w);
        }

        // ---- MFMA: 8 N-tiles x 2 K-halves ----
        f32x4 acc[8];
        #pragma unroll
        for (int t = 0; t < 8; ++t) {
            acc[t] = (f32x4){0.f, 0.f, 0.f, 0.f};
            acc[t] = __builtin_amdgcn_mfma_f32_16x16x32_bf16(a0, bfrag[t][0], acc[t], 0, 0, 0);
            acc[t] = __builtin_amdgcn_mfma_f32_16x16x32_bf16(a1, bfrag[t][1], acc[t], 0, 0, 0);
        }

        if (it > 0) __syncthreads();         // prev tile's eb reads done

        // ---- epilogue: C[row][col] -> LDS fp16 (add b1 on P cols) ----
        // C/D layout: col = lane&15 (=n), row = q*4 + reg (+ wave*16).
        #pragma unroll
        for (int t = 0; t < 8; ++t) {
            const float bb = (t == 0) ? bias_n : (t == 1) ? bias_n1
                           : (t == 2) ? bias_n2 : (t == 3) ? bias_n3 : 0.0f;
            #pragma unroll
            for (int r = 0; r < 4; ++r) {
                const int row = wave * 16 + q * 4 + r;
                eb[row * PADH + t * 16 + n] = __float2half(acc[t][r] + bb);
            }
        }
        __syncthreads();

        // ---- coalesced fp16 stores: cols 0..63 -> P, 64..127 -> Q ----
        #pragma unroll
        for (int s = 0; s < 4; ++s) {
            const int idx  = tid + s * 256;   // 0..1023 uint4s
            const int row  = idx >> 4;
            const int part = idx & 15;
            if (row < nrow) {
                const uint4 v = *(const uint4*)&eb[row * PADH + part * 8];
                __half* dstp = (part < 8)
                    ? (P + (size_t)(n0 + row) * HF + part * 8)
                    : (Q + (size_t)(n0 + row) * HF + (part - 8) * 8);
                *(uint4*)dstp = v;
            }
        }
    }
}

// ---------------- Phase 2: per-edge score (at gather floor) ----------------
__device__ __forceinline__ float dot8_relu(uint4 pv, uint4 qv, float4 wa, float4 wb) {
    const __half2* ph = (const __half2*)&pv;
    const __half2* qh = (const __half2*)&qv;
    const float2 p0 = __half22float2(ph[0]), q0 = __half22float2(qh[0]);
    const float2 p1 = __half22float2(ph[1]), q1 = __half22float2(qh[1]);
    const float2 p2 = __half22float2(ph[2]), q2 = __half22float2(qh[2]);
    const float2 p3 = __half22float2(ph[3]), q3 = __half22float2(qh[3]);
    float acc = 0.f;
    acc = fmaf(fmaxf(p0.x + q0.x, 0.f), wa.x, acc);
    acc = fmaf(fmaxf(p0.y + q0.y, 0.f), wa.y, acc);
    acc = fmaf(fmaxf(p1.x + q1.x, 0.f), wa.z, acc);
    acc = fmaf(fmaxf(p1.y + q1.y, 0.f), wa.w, acc);
    acc = fmaf(fmaxf(p2.x + q2.x, 0.f), wb.x, acc);
    acc = fmaf(fmaxf(p2.y + q2.y, 0.f), wb.y, acc);
    acc = fmaf(fmaxf(p3.x + q3.x, 0.f), wb.z, acc);
    acc = fmaf(fmaxf(p3.y + q3.y, 0.f), wb.w, acc);
    return acc;
}

__device__ __forceinline__ float red8(float v) {
    v += __shfl_xor(v, 4, 8);
    v += __shfl_xor(v, 2, 8);
    v += __shfl_xor(v, 1, 8);
    return v;
}

__global__ __launch_bounds__(256) void edge_score_kernel(
    const __half* __restrict__ P, const __half* __restrict__ Q,
    const int* __restrict__ src, const int* __restrict__ dst,
    const float* __restrict__ W2, const float* __restrict__ b2,
    float* __restrict__ out, int n_edges)
{
    const int tid   = blockIdx.x * 256 + threadIdx.x;
    const int sub   = threadIdx.x & 7;
    const int group = tid >> 3;
    const int j0    = sub * 8;
    const int e0    = group * 8;
    if (e0 >= n_edges) return;

    const float4 w2a = *(const float4*)(W2 + j0);
    const float4 w2b = *(const float4*)(W2 + j0 + 4);
    const float bias2 = b2[0];

    if (e0 + 8 <= n_edges) {
        const int4 sA = *(const int4*)(src + e0);
        const int4 sB = *(const int4*)(src + e0 + 4);
        const int4 dA = *(const int4*)(dst + e0);
        const int4 dB = *(const int4*)(dst + e0 + 4);

        const uint4 p0 = *(const uint4*)(P + (size_t)sA.x * HF + j0);
        const uint4 p1 = *(const uint4*)(P + (size_t)sA.y * HF + j0);
        const uint4 p2 = *(const uint4*)(P + (size_t)sA.z * HF + j0);
        const uint4 p3 = *(const uint4*)(P + (size_t)sA.w * HF + j0);
        const uint4 p4 = *(const uint4*)(P + (size_t)sB.x * HF + j0);
        const uint4 p5 = *(const uint4*)(P + (size_t)sB.y * HF + j0);
        const uint4 p6 = *(const uint4*)(P + (size_t)sB.z * HF + j0);
        const uint4 p7 = *(const uint4*)(P + (size_t)sB.w * HF + j0);
        const uint4 q0 = *(const uint4*)(Q + (size_t)dA.x * HF + j0);
        const uint4 q1 = *(const uint4*)(Q + (size_t)dA.y * HF + j0);
        const uint4 q2 = *(const uint4*)(Q + (size_t)dA.z * HF + j0);
        const uint4 q3 = *(const uint4*)(Q + (size_t)dA.w * HF + j0);
        const uint4 q4 = *(const uint4*)(Q + (size_t)dB.x * HF + j0);
        const uint4 q5 = *(const uint4*)(Q + (size_t)dB.y * HF + j0);
        const uint4 q6 = *(const uint4*)(Q + (size_t)dB.z * HF + j0);
        const uint4 q7 = *(const uint4*)(Q + (size_t)dB.w * HF + j0);

        float s0 = red8(dot8_relu(p0, q0, w2a, w2b));
        float s1 = red8(dot8_relu(p1, q1, w2a, w2b));
        float s2 = red8(dot8_relu(p2, q2, w2a, w2b));
        float s3 = red8(dot8_relu(p3, q3, w2a, w2b));
        float s4 = red8(dot8_relu(p4, q4, w2a, w2b));
        float s5 = red8(dot8_relu(p5, q5, w2a, w2b));
        float s6 = red8(dot8_relu(p6, q6, w2a, w2b));
        float s7 = red8(dot8_relu(p7, q7, w2a, w2b));

        if (sub == 0) {
            *(float4*)(out + e0)     = make_float4(s0 + bias2, s1 + bias2,
                                                   s2 + bias2, s3 + bias2);
            *(float4*)(out + e0 + 4) = make_float4(s4 + bias2, s5 + bias2,
                                                   s6 + bias2, s7 + bias2);
        }
    } else {
        for (int e = e0; e < n_edges; ++e) {
            const int s = src[e];
            const int d = dst[e];
            const uint4 pv = *(const uint4*)(P + (size_t)s * HF + j0);
            const uint4 qv = *(const uint4*)(Q + (size_t)d * HF + j0);
            float sc = red8(dot8_relu(pv, qv, w2a, w2b));
            if (sub == 0) out[e] = sc + bias2;
        }
    }
}

extern "C" void kernel_launch(void* const* d_in, const int* in_sizes, int n_in,
                              void* d_out, int out_size, void* d_ws, size_t ws_size,
                              hipStream_t stream) {
    const float* h   = (const float*)d_in[0];
    const int*   src = (const int*)d_in[1];
    const int*   dst = (const int*)d_in[2];
    const float* W1  = (const float*)d_in[3];
    const float* b1  = (const float*)d_in[4];
    const float* W2  = (const float*)d_in[5];
    const float* b2  = (const float*)d_in[6];
    float* out = (float*)d_out;

    const int n_nodes = in_sizes[0] / HF;
    const int n_edges = in_sizes[1];

    __half* P = (__half*)d_ws;
    __half* Q = P + (size_t)n_nodes * HF;

    const int ntiles   = (n_nodes + 63) / 64;
    const int nblocks1 = (ntiles + TPB - 1) / TPB;       // 2 tiles per block
    node_proj_kernel<<<nblocks1, 256, 0, stream>>>(h, W1, b1, P, Q, n_nodes);

    const int ngroups  = (n_edges + 7) / 8;              // 8 edges per 8-lane group
    const int nblocks2 = (ngroups + 31) / 32;            // 32 groups per 256-thr block
    edge_score_kernel<<<nblocks2, 256, 0, stream>>>(P, Q, src, dst, W2, b2, out, n_edges);
}